// Round 10
// baseline (152.640 us; speedup 1.0000x reference)
//
#include <hip/hip_runtime.h>
#include <hip/hip_bf16.h>

#define NN 8192
#define DD 128
#define BM 16
#define JS 8

typedef __attribute__((ext_vector_type(4))) float f32x4;
typedef __attribute__((ext_vector_type(8))) short bf16x8;
typedef __attribute__((ext_vector_type(4))) unsigned int u32x4;

__device__ __forceinline__ unsigned short f2bf(float x) {
    unsigned u = __float_as_uint(x);
    u += 0x7fffu + ((u >> 16) & 1u);   // round-to-nearest-even
    return (unsigned short)(u >> 16);
}

// ---------------------------------------------------------------------------
// Kernel A: h = z@W + B, PACKED fragment-linear (validated R9):
//   (n, j) -> hT[(j>>5)*4096 + (n>>4)*512 + ((j>>3)&3)*128 + (n&15)*8 + (j&7)]
// lane l, fragment f of K-group kt reads 8 bf16 at kt*4096 + f*512 + l*8.
// ---------------------------------------------------------------------------
__global__ void __launch_bounds__(256) h_transform(
    const float* __restrict__ z, const float* __restrict__ W,
    const float* __restrict__ Bv, unsigned short* __restrict__ hT) {
    __shared__ float zs[BM * DD];
    __shared__ float wt[DD * 132];
    const int t = threadIdx.x;
    const int j0 = blockIdx.x * BM;

    {
        const f32x4* zsrc = (const f32x4*)(z + (size_t)j0 * DD);
        f32x4* zdst = (f32x4*)zs;
        zdst[t] = zsrc[t];
        zdst[t + 256] = zsrc[t + 256];
    }
    for (int q = t; q < DD * 32; q += 256) {
        int k = q >> 5;
        int n0 = (q & 31) << 2;
        f32x4 wv = *(const f32x4*)(W + k * DD + n0);
        wt[(n0 + 0) * 132 + k] = wv[0];
        wt[(n0 + 1) * 132 + k] = wv[1];
        wt[(n0 + 2) * 132 + k] = wv[2];
        wt[(n0 + 3) * 132 + k] = wv[3];
    }
    __syncthreads();

    const int n = t >> 1;
    const int ja = (t & 1) << 3;
    float acc[8];
    float bn = Bv[n];
#pragma unroll
    for (int e = 0; e < 8; e++) acc[e] = bn;

#pragma unroll 8
    for (int k4 = 0; k4 < 32; ++k4) {
        f32x4 wv = *(const f32x4*)&wt[n * 132 + (k4 << 2)];
#pragma unroll
        for (int e = 0; e < 8; e++) {
            f32x4 zv = *(const f32x4*)&zs[(ja + e) * DD + (k4 << 2)];
            acc[e] += zv[0] * wv[0] + zv[1] * wv[1] + zv[2] * wv[2] + zv[3] * wv[3];
        }
    }

    const int j = j0 + ja;
    unsigned short* dst = hT + ((j >> 5) * 4096 + (n >> 4) * 512 +
                                (((j >> 3) & 3) << 7) + ((n & 15) << 3));
    uint4 uv;
    uv.x = (unsigned)f2bf(acc[0]) | ((unsigned)f2bf(acc[1]) << 16);
    uv.y = (unsigned)f2bf(acc[2]) | ((unsigned)f2bf(acc[3]) << 16);
    uv.z = (unsigned)f2bf(acc[4]) | ((unsigned)f2bf(acc[5]) << 16);
    uv.w = (unsigned)f2bf(acc[6]) | ((unsigned)f2bf(acc[7]) << 16);
    *(uint4*)dst = uv;
}

// ---------------------------------------------------------------------------
// Kernel S: pure streaming sens probe/producer. Tile = 16 rows x 1024 cols,
// 512 threads, 100% occupancy (32.25 KB LDS, 4 blocks/CU). dist read in
// 512 B runs; S computed; ONE LDS transpose pass (one barrier); written
// fragment-packed + fully linear (16 B/lane coalesced 8 KB runs):
//   S_pk[((rb*256 + jt*32 + g)*64 + l)*8 + e] = S(r0+(l&15), jc+g*32+(l>>4)*8+e)
// This is the closest possible analog of the 6.3 TB/s copy ubench that still
// does the required work -> isolates streaming from the fused structures.
// ---------------------------------------------------------------------------
__global__ void __launch_bounds__(512) sens_stream(
    const float* __restrict__ dist, const float* __restrict__ mu,
    const float* __restrict__ sigma, unsigned short* __restrict__ S_pk,
    int row0) {
    __shared__ char tile[16 * 2064];     // 16 rows x (2048 + 16 pad) B
    const int t = threadIdx.x;
    const int rb = (int)blockIdx.x >> 3;
    const int jt = (int)blockIdx.x & 7;
    const int r0 = row0 + rb * 16;
    const int jc = jt * 1024;

    const float inv_mu = 1.0f / mu[0];
    const float sg = sigma[0];
    const float ninv2s2 = -1.0f / (2.0f * sg * sg);

    const int tr = t >> 5;               // 0..15
    const int tc = (t & 31) << 2;        // 0..124
    const float* dp = dist + (size_t)(r0 + tr) * NN + jc + tc;
    const int rg = r0 + tr;

    f32x4 dv[8];
#pragma unroll
    for (int q = 0; q < 8; ++q) dv[q] = *(const f32x4*)(dp + q * 128);

    char* wp = tile + tr * 2064 + tc * 2;
#pragma unroll
    for (int q = 0; q < 8; ++q) {
        unsigned short hh[4];
#pragma unroll
        for (int e = 0; e < 4; ++e) {
            float d = dv[q][e];
            float qq = __builtin_amdgcn_rcpf(d) - inv_mu;
            float s = __expf(qq * qq * ninv2s2);
            bool keep = (d < 0.5f) & ((jc + tc + q * 128 + e) != rg);
            hh[e] = f2bf(keep ? s : 0.0f);
        }
        uint2 u;
        u.x = (unsigned)hh[0] | ((unsigned)hh[1] << 16);
        u.y = (unsigned)hh[2] | ((unsigned)hh[3] << 16);
        *(uint2*)(wp + q * 256) = u;
    }
    __syncthreads();

    // fragment-order readback, linear packed store
    char* ob = (char*)S_pk + (((size_t)rb * 256 + jt * 32) << 10) + t * 16;
#pragma unroll
    for (int p = 0; p < 4; ++p) {
        const int u = t + 512 * p;
        const int g = u >> 6;
        const int l = u & 63;
        bf16x8 v = *(const bf16x8*)(tile + (l & 15) * 2064 + g * 64 +
                                    ((l >> 4) << 4));
        *(bf16x8*)(ob + p * 8192) = v;
    }
}

// ---------------------------------------------------------------------------
// Kernel G: S_pk @ hT_pk -> partials. 1-wave blocks, 16 rows x 128 cols,
// K-slice 1024 (32 groups). EVERY load is a 1 KB contiguous coalesced run
// (both operands fragment-packed). S from L3-resident fresh chunk; hT from
// XCD-affine L2 (ks = bid&7). Depth-8 S / depth-3 hT static rotation, fully
// unrolled, zero barriers, zero conditionals. Over-prefetch at slice end
// lands harmlessly inside d_ws (S_pk is followed by partials).
// ---------------------------------------------------------------------------
__global__ void __launch_bounds__(64) gemm_pk(
    const unsigned short* __restrict__ S_pk,
    const unsigned short* __restrict__ hT, float* __restrict__ part,
    int row0) {
    const int l = threadIdx.x;
    const int ks = (int)blockIdx.x & 7;
    const int rt = (int)blockIdx.x >> 3;
    const int g0 = ks * 32;

    const char* sp = (const char*)S_pk + (((size_t)rt * 256 + g0) << 10) + l * 16;
    const unsigned short* hp = hT + (size_t)g0 * 4096 + l * 8;

    f32x4 acc[8];
#pragma unroll
    for (int f = 0; f < 8; ++f) acc[f] = (f32x4){0.f, 0.f, 0.f, 0.f};

    bf16x8 sA[8];
    u32x4 hS[3][8];

#pragma unroll
    for (int i = 0; i < 8; ++i)
        sA[i] = *(const bf16x8*)(sp + i * 1024);
#pragma unroll
    for (int j = 0; j < 3; ++j)
#pragma unroll
        for (int f = 0; f < 8; ++f)
            hS[j][f] = *(const u32x4*)(hp + (size_t)j * 4096 + f * 512);

#pragma unroll
    for (int gg = 0; gg < 32; ++gg) {
        const int ss = gg & 7;
        const int hs = gg % 3;
        bf16x8 a = sA[ss];
#pragma unroll
        for (int f = 0; f < 8; ++f)
            acc[f] = __builtin_amdgcn_mfma_f32_16x16x32_bf16(
                a, __builtin_bit_cast(bf16x8, hS[hs][f]), acc[f], 0, 0, 0);
        sA[ss] = *(const bf16x8*)(sp + (gg + 8) * 1024);
#pragma unroll
        for (int f = 0; f < 8; ++f)
            hS[hs][f] = *(const u32x4*)(hp + (size_t)(gg + 3) * 4096 + f * 512);
    }

    // epilogue (validated C-layout: col = lane&15, row = (lane>>4)*4 + rr)
    float* po = part + (size_t)ks * (NN * DD);
    const int orow = row0 + rt * 16 + ((l >> 4) << 2);
    const int ocol = l & 15;
#pragma unroll
    for (int f = 0; f < 8; ++f)
#pragma unroll
        for (int rr = 0; rr < 4; ++rr)
            po[(size_t)(orow + rr) * DD + f * 16 + ocol] = acc[f][rr];
}

// ---------------------------------------------------------------------------
// Kernel C: sum the 8 K-split partials into out.
// ---------------------------------------------------------------------------
__global__ void __launch_bounds__(256) reduce_part(
    const float* __restrict__ part, float* __restrict__ outp) {
    const size_t idx = ((size_t)blockIdx.x * 256 + threadIdx.x) << 2;
    f32x4 s = *(const f32x4*)(part + idx);
#pragma unroll
    for (int ksp = 1; ksp < JS; ++ksp)
        s += *(const f32x4*)(part + (size_t)ksp * (NN * DD) + idx);
    *(f32x4*)(outp + idx) = s;
}

extern "C" void kernel_launch(void* const* d_in, const int* in_sizes, int n_in,
                              void* d_out, int out_size, void* d_ws, size_t ws_size,
                              hipStream_t stream) {
    const float* z = (const float*)d_in[0];
    const float* dist = (const float*)d_in[1];
    const float* W = (const float*)d_in[2];
    const float* Bv = (const float*)d_in[3];
    const float* mu = (const float*)d_in[4];
    const float* sigma = (const float*)d_in[5];
    float* out = (float*)d_out;

    const size_t hT_bytes = (size_t)DD * NN * 2;                // 2 MB
    const size_t part_bytes = (size_t)JS * NN * DD * 4;         // 32 MB

    // chunk rows so hT + S_pk chunk + partials fit in ws
    int nq = 4;
    while (nq < 64 &&
           hT_bytes + ((size_t)(NN / nq) * NN * 2) + part_bytes > ws_size)
        nq <<= 1;
    const int rows = NN / nq;
    const size_t spk_bytes = (size_t)rows * NN * 2;

    unsigned short* hT = (unsigned short*)d_ws;
    unsigned short* S_pk = (unsigned short*)((char*)d_ws + hT_bytes);
    float* part = (float*)((char*)d_ws + hT_bytes + spk_bytes);

    h_transform<<<NN / BM, 256, 0, stream>>>(z, W, Bv, hT);
    for (int q = 0; q < nq; ++q) {
        sens_stream<<<(rows / 16) * 8, 512, 0, stream>>>(dist, mu, sigma,
                                                         S_pk, q * rows);
        gemm_pk<<<(rows / 16) * 8, 64, 0, stream>>>(S_pk, hT, part, q * rows);
    }
    reduce_part<<<(NN * DD) / 1024, 256, 0, stream>>>(part, out);
}

// Round 11
// 147.354 us; speedup vs baseline: 1.0359x; 1.0359x over previous
//
#include <hip/hip_runtime.h>
#include <hip/hip_bf16.h>

#define NN 8192
#define DD 128
#define BM 16
#define JS 8            // j-slices (K-split of the reduction)
#define RPB 128         // output rows per block
#define JSLICE 1024     // j columns per block
#define JCHUNK 256      // j columns per LDS stage (66 KB -> 2 blocks/CU)
#define LSTR 528        // LDS bytes per n-row: 256*2 + 16 pad

typedef __attribute__((ext_vector_type(4))) float f32x4;
typedef __attribute__((ext_vector_type(8))) short bf16x8;

__device__ __forceinline__ unsigned short f2bf(float x) {
    unsigned u = __float_as_uint(x);
    u += 0x7fffu + ((u >> 16) & 1u);   // round-to-nearest-even
    return (unsigned short)(u >> 16);
}

// ---------------------------------------------------------------------------
// Kernel A: hT[n][j] = bf16( B[n] + sum_k z[j][k] * W[k][n] ), plain layout.
// ---------------------------------------------------------------------------
__global__ void __launch_bounds__(256) h_transform(
    const float* __restrict__ z, const float* __restrict__ W,
    const float* __restrict__ Bv, unsigned short* __restrict__ hT) {
    __shared__ float zs[BM * DD];
    __shared__ float wt[DD * 132];
    const int t = threadIdx.x;
    const int j0 = blockIdx.x * BM;

    {
        const f32x4* zsrc = (const f32x4*)(z + (size_t)j0 * DD);
        f32x4* zdst = (f32x4*)zs;
        zdst[t] = zsrc[t];
        zdst[t + 256] = zsrc[t + 256];
    }
    for (int q = t; q < DD * 32; q += 256) {
        int k = q >> 5;
        int n0 = (q & 31) << 2;
        f32x4 wv = *(const f32x4*)(W + k * DD + n0);
        wt[(n0 + 0) * 132 + k] = wv[0];
        wt[(n0 + 1) * 132 + k] = wv[1];
        wt[(n0 + 2) * 132 + k] = wv[2];
        wt[(n0 + 3) * 132 + k] = wv[3];
    }
    __syncthreads();

    const int n = t >> 1;
    const int ja = (t & 1) << 3;
    float acc[8];
    float bn = Bv[n];
#pragma unroll
    for (int e = 0; e < 8; e++) acc[e] = bn;

#pragma unroll 8
    for (int k4 = 0; k4 < 32; ++k4) {
        f32x4 wv = *(const f32x4*)&wt[n * 132 + (k4 << 2)];
#pragma unroll
        for (int e = 0; e < 8; e++) {
            f32x4 zv = *(const f32x4*)&zs[(ja + e) * DD + (k4 << 2)];
            acc[e] += zv[0] * wv[0] + zv[1] * wv[1] + zv[2] * wv[2] + zv[3] * wv[3];
        }
    }

    const int j = j0 + ja;
    unsigned short* dst = hT + (size_t)n * NN + j;
    uint4 uv;
    uv.x = (unsigned)f2bf(acc[0]) | ((unsigned)f2bf(acc[1]) << 16);
    uv.y = (unsigned)f2bf(acc[2]) | ((unsigned)f2bf(acc[3]) << 16);
    uv.z = (unsigned)f2bf(acc[4]) | ((unsigned)f2bf(acc[5]) << 16);
    uv.w = (unsigned)f2bf(acc[6]) | ((unsigned)f2bf(acc[7]) << 16);
    *(uint4*)dst = uv;
}

// ---------------------------------------------------------------------------
// Kernel B: R4 structure with HALVED LDS tile -> 2 blocks/CU overlap.
// Grid: 64 rowblocks x 8 jslices = 512 blocks (2/CU). Block: 512 thr =
// 8 waves x 16 rows. hT tile [128 n][256 j] in LDS (66 KB, 16 B row pad),
// staged 4x per block; S computed in-register from fragment-layout dist
// loads (validated R2/R4 path); 2 barriers per chunk.
// ---------------------------------------------------------------------------
__global__ void __launch_bounds__(512, 4) fused_interact(
    const float* __restrict__ dist, const unsigned short* __restrict__ hT,
    const float* __restrict__ mu, const float* __restrict__ sigma,
    float* __restrict__ part) {
    __shared__ char hs[DD * LSTR];       // 128 rows x 528 B = 66 KB

    const int t = threadIdx.x;
    const int w = t >> 6;
    const int l = t & 63;
    const int rb = (int)blockIdx.x >> 3;
    const int js = (int)blockIdx.x & 7;
    const int r0 = rb * RPB;
    const int rbase = r0 + w * 16;

    const int row = l & 15;              // A-frag row within wave
    const int kc8 = (l >> 4) << 3;       // A-frag k-offset (elements)
    const int q16 = (l >> 4) << 4;       // B-frag k-offset (bytes)

    const float inv_mu = 1.0f / mu[0];
    const float sg = sigma[0];
    const float ninv2s2 = -1.0f / (2.0f * sg * sg);

    const float* dp0 = dist + (size_t)(rbase + row) * NN + kc8;
    const int diag0 = rbase + row;
    const char* hbase = hs + row * LSTR + q16;   // + f*16*LSTR + lk

    f32x4 acc[8];
#pragma unroll
    for (int f = 0; f < 8; ++f) acc[f] = (f32x4){0.f, 0.f, 0.f, 0.f};

    f32x4 dAa, dAb, dBa, dBb;

#define LOADD(Da, Db, K)                                                     \
    do {                                                                     \
        Da = *(const f32x4*)(dp0 + (K));                                     \
        Db = *(const f32x4*)(dp0 + (K) + 4);                                 \
    } while (0)

#define COMPUTE(Da, Db, K, LK)                                               \
    do {                                                                     \
        float v0[4] = {Da[0], Da[1], Da[2], Da[3]};                          \
        float v1[4] = {Db[0], Db[1], Db[2], Db[3]};                          \
        unsigned short hh[8];                                                \
        _Pragma("unroll") for (int e = 0; e < 4; ++e) {                      \
            float d = v0[e];                                                 \
            float qq = __builtin_amdgcn_rcpf(d) - inv_mu;                    \
            float s = __expf(qq * qq * ninv2s2);                             \
            bool keep = (d < 0.5f) & (((K) + kc8 + e) != diag0);             \
            hh[e] = f2bf(keep ? s : 0.0f);                                   \
        }                                                                    \
        _Pragma("unroll") for (int e = 0; e < 4; ++e) {                      \
            float d = v1[e];                                                 \
            float qq = __builtin_amdgcn_rcpf(d) - inv_mu;                    \
            float s = __expf(qq * qq * ninv2s2);                             \
            bool keep = (d < 0.5f) & (((K) + kc8 + 4 + e) != diag0);         \
            hh[4 + e] = f2bf(keep ? s : 0.0f);                               \
        }                                                                    \
        uint4 au;                                                            \
        au.x = (unsigned)hh[0] | ((unsigned)hh[1] << 16);                    \
        au.y = (unsigned)hh[2] | ((unsigned)hh[3] << 16);                    \
        au.z = (unsigned)hh[4] | ((unsigned)hh[5] << 16);                    \
        au.w = (unsigned)hh[6] | ((unsigned)hh[7] << 16);                    \
        bf16x8 a0 = __builtin_bit_cast(bf16x8, au);                          \
        _Pragma("unroll") for (int f = 0; f < 8; ++f) {                      \
            bf16x8 bb = *(const bf16x8*)(hbase + f * (16 * LSTR) + (LK));    \
            acc[f] = __builtin_amdgcn_mfma_f32_16x16x32_bf16(a0, bb, acc[f], \
                                                             0, 0, 0);       \
        }                                                                    \
    } while (0)

#pragma unroll 1
    for (int chunk = 0; chunk < JSLICE / JCHUNK; ++chunk) {
        const int jc = js * JSLICE + chunk * JCHUNK;

        // issue staging loads before the barrier (overlap with own compute
        // tail and the co-resident block)
        uint4 tmp[8];
#pragma unroll
        for (int i = 0; i < 8; ++i) {
            int c = i * 512 + t;
            int n = c >> 5;          // 32 uint4 per n-row
            int cb = c & 31;
            tmp[i] = *(const uint4*)(hT + (size_t)n * NN + jc + cb * 8);
        }
        __syncthreads();   // all waves done reading previous tile
#pragma unroll
        for (int i = 0; i < 8; ++i) {
            int c = i * 512 + t;
            int n = c >> 5;
            int cb = c & 31;
            *(uint4*)(hs + n * LSTR + cb * 16) = tmp[i];
        }
        __syncthreads();   // tile ready

        LOADD(dAa, dAb, jc);
        LOADD(dBa, dBb, jc + 32);
#pragma unroll 1
        for (int it = 0; it < 8; it += 2) {
            const int kg = jc + (it << 5);
            const int lk = it << 6;
            COMPUTE(dAa, dAb, kg, lk);
            if (it + 2 < 8) LOADD(dAa, dAb, kg + 64);
            COMPUTE(dBa, dBb, kg + 32, lk + 64);
            if (it + 3 < 8) LOADD(dBa, dBb, kg + 96);
        }
    }
#undef LOADD
#undef COMPUTE

    // epilogue (validated C-layout: col = lane&15, row = (lane>>4)*4 + rr)
    float* po = part + (size_t)js * (NN * DD);
    const int orow = rbase + ((l >> 4) << 2);
    const int ocol = l & 15;
#pragma unroll
    for (int f = 0; f < 8; ++f)
#pragma unroll
        for (int rr = 0; rr < 4; ++rr)
            po[(size_t)(orow + rr) * DD + f * 16 + ocol] = acc[f][rr];
}

// ---------------------------------------------------------------------------
// Kernel C: sum the 8 K-split partials into out.
// ---------------------------------------------------------------------------
__global__ void __launch_bounds__(256) reduce_part(
    const float* __restrict__ part, float* __restrict__ outp) {
    const size_t idx = ((size_t)blockIdx.x * 256 + threadIdx.x) << 2;
    f32x4 s = *(const f32x4*)(part + idx);
#pragma unroll
    for (int ksp = 1; ksp < JS; ++ksp)
        s += *(const f32x4*)(part + (size_t)ksp * (NN * DD) + idx);
    *(f32x4*)(outp + idx) = s;
}

extern "C" void kernel_launch(void* const* d_in, const int* in_sizes, int n_in,
                              void* d_out, int out_size, void* d_ws, size_t ws_size,
                              hipStream_t stream) {
    const float* z = (const float*)d_in[0];
    const float* dist = (const float*)d_in[1];
    const float* W = (const float*)d_in[2];
    const float* Bv = (const float*)d_in[3];
    const float* mu = (const float*)d_in[4];
    const float* sigma = (const float*)d_in[5];
    float* out = (float*)d_out;

    unsigned short* hT = (unsigned short*)d_ws;                 // 2 MB
    const size_t hT_bytes = (size_t)DD * NN * 2;
    float* part = (float*)((char*)d_ws + hT_bytes);             // 8 x 4 MB

    h_transform<<<NN / BM, 256, 0, stream>>>(z, W, Bv, hT);
    fused_interact<<<(NN / RPB) * JS, 512, 0, stream>>>(dist, hT, mu, sigma,
                                                        part);
    reduce_part<<<(NN * DD) / 1024, 256, 0, stream>>>(part, out);
}

// Round 12
// 145.100 us; speedup vs baseline: 1.0520x; 1.0155x over previous
//
#include <hip/hip_runtime.h>
#include <hip/hip_bf16.h>

#define NN 8192
#define DD 128
#define BM 16
#define JS 8
#define GSTR 1040          // LDS bytes per k-group block (1024 + 16 pad)

typedef __attribute__((ext_vector_type(4))) float f32x4;
typedef __attribute__((ext_vector_type(8))) short bf16x8;
typedef __attribute__((ext_vector_type(4))) unsigned int u32x4;

__device__ __forceinline__ unsigned short f2bf(float x) {
    unsigned u = __float_as_uint(x);
    u += 0x7fffu + ((u >> 16) & 1u);   // round-to-nearest-even
    return (unsigned short)(u >> 16);
}

// ---------------------------------------------------------------------------
// Kernel A (validated R9/R10): h = z@W + B, PACKED fragment-linear:
//   (n, j) -> hT[(j>>5)*4096 + (n>>4)*512 + ((j>>3)&3)*128 + (n&15)*8 + (j&7)]
// lane l, fragment f of K-group kt reads 8 bf16 at kt*4096 + f*512 + l*8.
// ---------------------------------------------------------------------------
__global__ void __launch_bounds__(256) h_transform(
    const float* __restrict__ z, const float* __restrict__ W,
    const float* __restrict__ Bv, unsigned short* __restrict__ hT) {
    __shared__ float zs[BM * DD];
    __shared__ float wt[DD * 132];
    const int t = threadIdx.x;
    const int j0 = blockIdx.x * BM;

    {
        const f32x4* zsrc = (const f32x4*)(z + (size_t)j0 * DD);
        f32x4* zdst = (f32x4*)zs;
        zdst[t] = zsrc[t];
        zdst[t + 256] = zsrc[t + 256];
    }
    for (int q = t; q < DD * 32; q += 256) {
        int k = q >> 5;
        int n0 = (q & 31) << 2;
        f32x4 wv = *(const f32x4*)(W + k * DD + n0);
        wt[(n0 + 0) * 132 + k] = wv[0];
        wt[(n0 + 1) * 132 + k] = wv[1];
        wt[(n0 + 2) * 132 + k] = wv[2];
        wt[(n0 + 3) * 132 + k] = wv[3];
    }
    __syncthreads();

    const int n = t >> 1;
    const int ja = (t & 1) << 3;
    float acc[8];
    float bn = Bv[n];
#pragma unroll
    for (int e = 0; e < 8; e++) acc[e] = bn;

#pragma unroll 8
    for (int k4 = 0; k4 < 32; ++k4) {
        f32x4 wv = *(const f32x4*)&wt[n * 132 + (k4 << 2)];
#pragma unroll
        for (int e = 0; e < 8; e++) {
            f32x4 zv = *(const f32x4*)&zs[(ja + e) * DD + (k4 << 2)];
            acc[e] += zv[0] * wv[0] + zv[1] * wv[1] + zv[2] * wv[2] + zv[3] * wv[3];
        }
    }

    const int j = j0 + ja;
    unsigned short* dst = hT + ((j >> 5) * 4096 + (n >> 4) * 512 +
                                (((j >> 3) & 3) << 7) + ((n & 15) << 3));
    uint4 uv;
    uv.x = (unsigned)f2bf(acc[0]) | ((unsigned)f2bf(acc[1]) << 16);
    uv.y = (unsigned)f2bf(acc[2]) | ((unsigned)f2bf(acc[3]) << 16);
    uv.z = (unsigned)f2bf(acc[4]) | ((unsigned)f2bf(acc[5]) << 16);
    uv.w = (unsigned)f2bf(acc[6]) | ((unsigned)f2bf(acc[7]) << 16);
    *(uint4*)dst = uv;
}

// ---------------------------------------------------------------------------
// Kernel B: fused S + S@h with STRICT VMEM ISSUE-ORDER DISCIPLINE.
// vmcnt retires in issue order: waiting on a late-issued fast (L2) load
// forces all earlier-issued slow (HBM) loads to complete. Every prior round
// accidentally inverted this. Here, per chunk iteration:
//   writeS -> lgkmcnt(0)+s_barrier -> hT issues (fast, FIRST) -> MFMA
//   -> COMPS(c+1) (waits dist issued one full iter ago; only newer
//      outstanding = this iter's nothing-slow) -> dist issue for c+2
//      (slow, LAST) -> s_barrier (raw: does NOT drain vmcnt).
// Block = 8 waves x 16 rows, full K=8192 (8 chunks of 1024). Wave w produces
// S rows 2w,2w+1 from fully-coalesced 1 KB dist loads; consumes k-groups
// w*4..w*4+3 per chunk via MFMA (A from LDS: lgkm domain, vmcnt-neutral).
// Partials indexed by wave (8), reusing the validated reduce.
// ---------------------------------------------------------------------------
__global__ void __launch_bounds__(512) fused_interact(
    const float* __restrict__ dist, const unsigned short* __restrict__ hT,
    const float* __restrict__ mu, const float* __restrict__ sigma,
    float* __restrict__ part) {
    __shared__ uint4 sfr4[(32 * GSTR) / 16];   // 33.3 KB S tile
    char* sfr = (char*)sfr4;

    const int t = threadIdx.x;
    const int w = t >> 6;
    const int l = t & 63;
    const int r0 = (int)blockIdx.x * 16;

    const float inv_mu = 1.0f / mu[0];
    const float sg = sigma[0];
    const float ninv2s2 = -1.0f / (2.0f * sg * sg);

    const float* dp0 = dist + (size_t)(r0 + 2 * w) * NN + 4 * l;
    const float* dp1 = dp0 + NN;
    const unsigned short* hTb = hT + l * 8;

    // S-tile producer write base: element col C of local row r15 in group G
    // lives at G*GSTR + ((ke>>3)*16 + r15)*16 + (ke&7)*2, ke = C&31.
    // Lane l (load i): G = i*8+(l>>3), ke = 4*(l&7)+e -> uint2 per (row,i).
    const int wbase = (l >> 3) * GSTR + ((l & 7) >> 1) * 256 + (l & 1) * 8 +
                      (2 * w) * 16;
    // consumer A-frag: lane reads slot l of its group (row=l&15, ke=(l>>4)*8+m)
    const int abase = (w * 4) * GSTR + l * 16;

    f32x4 acc[8];
#pragma unroll
    for (int f = 0; f < 8; ++f) acc[f] = (f32x4){0.f, 0.f, 0.f, 0.f};

    f32x4 dvA[2][4], dvB[2][4];
    uint2 sv[2][4];
    u32x4 hb[2][8];

#define LOADDIST(DV, C)                                                      \
    do {                                                                     \
        _Pragma("unroll") for (int i_ = 0; i_ < 4; ++i_) {                   \
            DV[0][i_] = *(const f32x4*)(dp0 + (C) * 1024 + i_ * 256);        \
            DV[1][i_] = *(const f32x4*)(dp1 + (C) * 1024 + i_ * 256);        \
        }                                                                    \
    } while (0)

#define COMPS(DV, C)                                                         \
    do {                                                                     \
        _Pragma("unroll") for (int r_ = 0; r_ < 2; ++r_) {                   \
            const int diag_ = r0 + 2 * w + r_;                               \
            _Pragma("unroll") for (int i_ = 0; i_ < 4; ++i_) {               \
                unsigned short hh[4];                                        \
                _Pragma("unroll") for (int e_ = 0; e_ < 4; ++e_) {           \
                    float d = DV[r_][i_][e_];                                \
                    float qq = __builtin_amdgcn_rcpf(d) - inv_mu;            \
                    float s = __expf(qq * qq * ninv2s2);                     \
                    bool keep = (d < 0.5f) &                                 \
                                (((C) * 1024 + i_ * 256 + 4 * l + e_) !=     \
                                 diag_);                                     \
                    hh[e_] = f2bf(keep ? s : 0.0f);                          \
                }                                                            \
                sv[r_][i_].x = (unsigned)hh[0] | ((unsigned)hh[1] << 16);    \
                sv[r_][i_].y = (unsigned)hh[2] | ((unsigned)hh[3] << 16);    \
            }                                                                \
        }                                                                    \
    } while (0)

#define WRITES()                                                             \
    do {                                                                     \
        _Pragma("unroll") for (int r_ = 0; r_ < 2; ++r_)                     \
            _Pragma("unroll") for (int i_ = 0; i_ < 4; ++i_)                 \
                *(uint2*)(sfr + wbase + i_ * (8 * GSTR) + r_ * 16) =         \
                    sv[r_][i_];                                              \
    } while (0)

#define HTISS(GI, C)                                                         \
    do {                                                                     \
        const unsigned short* hp_ =                                          \
            hTb + ((C) * 32 + w * 4 + (GI)) * 4096;                          \
        _Pragma("unroll") for (int f_ = 0; f_ < 8; ++f_)                     \
            hb[(GI) & 1][f_] = *(const u32x4*)(hp_ + f_ * 512);              \
    } while (0)

#define MFMAG(GI)                                                            \
    do {                                                                     \
        bf16x8 a_ = *(const bf16x8*)(sfr + abase + (GI) * GSTR);             \
        _Pragma("unroll") for (int f_ = 0; f_ < 8; ++f_)                     \
            acc[f_] = __builtin_amdgcn_mfma_f32_16x16x32_bf16(               \
                a_, __builtin_bit_cast(bf16x8, hb[(GI) & 1][f_]), acc[f_],   \
                0, 0, 0);                                                    \
    } while (0)

#define BODY(C, DVF, DVH)                                                    \
    do {                                                                     \
        WRITES();                                                            \
        asm volatile("s_waitcnt lgkmcnt(0)" ::: "memory");                   \
        __builtin_amdgcn_s_barrier();                                        \
        HTISS(0, C);                                                         \
        HTISS(1, C);                                                         \
        MFMAG(0);                                                            \
        HTISS(2, C);                                                         \
        MFMAG(1);                                                            \
        HTISS(3, C);                                                         \
        MFMAG(2);                                                            \
        MFMAG(3);                                                            \
        __builtin_amdgcn_sched_barrier(0);                                   \
        COMPS(DVH, (C) + 1);                                                 \
        __builtin_amdgcn_sched_barrier(0);                                   \
        LOADDIST(DVF, ((C) + 2) & 7);                                        \
        asm volatile("" ::: "memory");                                       \
        __builtin_amdgcn_s_barrier();                                        \
    } while (0)

    // prologue: chunks 0,1 in flight; S(0) computed
    LOADDIST(dvA, 0);
    LOADDIST(dvB, 1);
    COMPS(dvA, 0);

#pragma unroll 1
    for (int c = 0; c < 8; c += 2) {
        BODY(c, dvA, dvB);       // writes S(c), computes S(c+1), loads c+2
        BODY(c + 1, dvB, dvA);   // writes S(c+1), computes S(c+2), loads c+3
    }
#undef LOADDIST
#undef COMPS
#undef WRITES
#undef HTISS
#undef MFMAG
#undef BODY

    // epilogue (validated C-layout: col = lane&15, row = (lane>>4)*4 + rr)
    float* po = part + (size_t)w * (NN * DD);
    const int orow = r0 + ((l >> 4) << 2);
    const int ocol = l & 15;
#pragma unroll
    for (int f = 0; f < 8; ++f)
#pragma unroll
        for (int rr = 0; rr < 4; ++rr)
            po[(size_t)(orow + rr) * DD + f * 16 + ocol] = acc[f][rr];
}

// ---------------------------------------------------------------------------
// Kernel C: sum the 8 per-wave partials into out.
// ---------------------------------------------------------------------------
__global__ void __launch_bounds__(256) reduce_part(
    const float* __restrict__ part, float* __restrict__ outp) {
    const size_t idx = ((size_t)blockIdx.x * 256 + threadIdx.x) << 2;
    f32x4 s = *(const f32x4*)(part + idx);
#pragma unroll
    for (int ksp = 1; ksp < JS; ++ksp)
        s += *(const f32x4*)(part + (size_t)ksp * (NN * DD) + idx);
    *(f32x4*)(outp + idx) = s;
}

extern "C" void kernel_launch(void* const* d_in, const int* in_sizes, int n_in,
                              void* d_out, int out_size, void* d_ws, size_t ws_size,
                              hipStream_t stream) {
    const float* z = (const float*)d_in[0];
    const float* dist = (const float*)d_in[1];
    const float* W = (const float*)d_in[2];
    const float* Bv = (const float*)d_in[3];
    const float* mu = (const float*)d_in[4];
    const float* sigma = (const float*)d_in[5];
    float* out = (float*)d_out;

    unsigned short* hT = (unsigned short*)d_ws;                 // 2 MB packed
    const size_t hT_bytes = (size_t)DD * NN * 2;
    float* part = (float*)((char*)d_ws + hT_bytes);             // 8 x 4 MB

    h_transform<<<NN / BM, 256, 0, stream>>>(z, W, Bv, hT);
    fused_interact<<<NN / 16, 512, 0, stream>>>(dist, hT, mu, sigma, part);
    reduce_part<<<(NN * DD) / 1024, 256, 0, stream>>>(part, out);
}